// Round 6
// baseline (112.459 us; speedup 1.0000x reference)
//
#include <hip/hip_runtime.h>

// Problem constants
#define IMG_H 512
#define IMG_W 512
#define IMG_SZ (IMG_H * IMG_W)
#define NKH 32
#define NKW 32
#define NK 1024
#define BATCH 64
#define NTT 33               // 16x16 tiles per dim of 528x528 padded image
#define NTILE (NTT * NTT)    // 1089
#define BG 4                 // batch groups of 16
#define NBLK (NTILE * BG)    // 4356

typedef __attribute__((address_space(3))) char lds_char_t;
typedef const __attribute__((address_space(1))) char g_char_t;

// out[b][n] = bias[n]  (main kernel atomically accumulates onto this)
__global__ __launch_bounds__(256)
void bslc_init(const float* __restrict__ bias, float* __restrict__ out)
{
    const int g = blockIdx.x * 256 + threadIdx.x;   // b*1024 + n
    out[g] = bias[g & (NK - 1)];
}

// Tile (tr,tc) = quadrant (qr,qc) of window (tr-qr, tc-qc): bijective.
// Block = one tile x 16 batches. LDS 16KB -> 8 blocks/CU.
// Stage (interior): async global_load_lds, 4 instrs/wave. LDS row bl is
// LINEAR (DMA writes base+lane*16); lane l's GLOBAL address is pre-swizzled
// to chunk c = l ^ bl (involution), so reads use slot = chunk ^ bl.
// Compute: wave = quadrant q; lane = (part p, batch bl). Each lane dots 16
// chunks; shfl_xor(16,32) combines parts; lanes 0..15 atomicAdd out[b][n].
__global__ __launch_bounds__(256, 8)
void bslc_main(const float* __restrict__ x,
               const float* __restrict__ w,
               float* __restrict__ out)
{
    __shared__ float4 xs[16 * 64];   // 16 KiB: [bl][slot], slot = chunk ^ bl

    // Bijective XCD-chunked swizzle (m204): 4356 = 8*544 + 4.
    const int hw = blockIdx.x;
    const int xcd = hw & 7, sl = hw >> 3;
    const int q8 = NBLK >> 3, r8 = NBLK & 7;          // 544, 4
    const int work = (xcd < r8 ? xcd * (q8 + 1)
                               : r8 * (q8 + 1) + (xcd - r8) * q8) + sl;

    const int bg  = work & 3;        // adjacent bg + neighbor tiles same XCD
    const int lin = work >> 2;
    const int tr = lin / NTT, tc = lin % NTT;

    const int t = threadIdx.x, lane = t & 63, wv = t >> 6;

    const int r0 = tr * 16 - 8, c0 = tc * 16 - 8;
    const bool interior = (tr >= 1) & (tr <= 31) & (tc >= 1) & (tc <= 31);

    if (interior) {
#pragma unroll
        for (int ii = 0; ii < 4; ++ii) {
            const int bl = 4 * ii + wv;              // wave-uniform
            const int c  = lane ^ bl;                // chunk this lane fetches
            const int rimg = r0 + (c >> 2);
            const int cimg = c0 + (c & 3) * 4;
            const float* gp = x + (size_t)(bg * 16 + bl) * IMG_SZ
                            + (size_t)rimg * IMG_W + cimg;
            __builtin_amdgcn_global_load_lds(
                (g_char_t*)gp, (lds_char_t*)&xs[bl * 64], 16, 0, 0);
        }
    } else {
#pragma unroll
        for (int ii = 0; ii < 4; ++ii) {
            const int bl = 4 * ii + wv;
            const int c  = lane ^ bl;
            const int rimg = r0 + (c >> 2);
            const int cimg = c0 + (c & 3) * 4;
            float4 v = make_float4(0.f, 0.f, 0.f, 0.f);
            if (rimg >= 0 && rimg < IMG_H && cimg >= 0 && cimg < IMG_W)
                v = *reinterpret_cast<const float4*>(
                    x + (size_t)(bg * 16 + bl) * IMG_SZ
                      + (size_t)rimg * IMG_W + cimg);
            xs[bl * 64 + lane] = v;                  // slot=lane, chunk=lane^bl
        }
    }
    __syncthreads();

    // ---------------- compute ----------------
    const int qr = wv >> 1, qc = wv & 1;
    const int nr = tr - qr, nc = tc - qc;
    if (nr < 0 || nr >= NKH || nc < 0 || nc >= NKW) return;  // wave-uniform
    const int n = nr * NKW + nc;

    const int p  = lane >> 4;        // part 0..3 (16 chunks each)
    const int bl = lane & 15;        // batch within block
    // Quadrant weight base: rows qr*16 + (kq>>2), cols qc*16 + (kq&3)*4.
    const float* wq = w + (size_t)n * 1024 + (size_t)(qr * 16) * 32 + qc * 16;

    float a0 = 0.f, a1 = 0.f, a2 = 0.f, a3 = 0.f;
#pragma unroll
    for (int j = 0; j < 16; ++j) {
        const int kq = p * 16 + j;
        const float4 xv  = xs[bl * 64 + (kq ^ bl)];
        const float4 wv4 = *reinterpret_cast<const float4*>(
            wq + (kq >> 2) * 32 + (kq & 3) * 4);     // 4 addrs/wave-instr
        a0 = fmaf(xv.x, wv4.x, a0);
        a1 = fmaf(xv.y, wv4.y, a1);
        a2 = fmaf(xv.z, wv4.z, a2);
        a3 = fmaf(xv.w, wv4.w, a3);
    }
    float s = (a0 + a1) + (a2 + a3);
    s += __shfl_xor(s, 16, 64);                      // combine parts
    s += __shfl_xor(s, 32, 64);
    if (p == 0)                                      // lanes 0..15: batch bl
        atomicAdd(&out[(size_t)(bg * 16 + bl) * NK + n], s);
}

extern "C" void kernel_launch(void* const* d_in, const int* in_sizes, int n_in,
                              void* d_out, int out_size, void* d_ws, size_t ws_size,
                              hipStream_t stream) {
    const float* x    = (const float*)d_in[0];  // (64,1,512,512) fp32
    const float* wgt  = (const float*)d_in[1];  // (1024,1024) fp32
    const float* bias = (const float*)d_in[2];  // (1024,) fp32
    float* out        = (float*)d_out;          // (64,32,32) fp32

    bslc_init<<<dim3(BATCH * NK / 256), 256, 0, stream>>>(bias, out);
    bslc_main<<<dim3(NBLK), 256, 0, stream>>>(x, wgt, out);
}

// Round 7
// 107.596 us; speedup vs baseline: 1.0452x; 1.0452x over previous
//
#include <hip/hip_runtime.h>

// Problem constants
#define IMG_H 512
#define IMG_W 512
#define IMG_SZ (IMG_H * IMG_W)
#define NKH 32
#define NKW 32
#define NK 1024
#define BATCH 64
#define NTT 33               // 16x16 tiles per dim of 528x528 padded image
#define NTILE (NTT * NTT)    // 1089
#define BG 4                 // batch groups of 16
#define NBLK (NTILE * BG)    // 4356

typedef __attribute__((address_space(3))) char lds_char_t;
typedef const __attribute__((address_space(1))) char g_char_t;

// out[b][n] = bias[n]  (main kernel atomically accumulates onto this)
__global__ __launch_bounds__(256)
void bslc_init(const float* __restrict__ bias, float* __restrict__ out)
{
    const int g = blockIdx.x * 256 + threadIdx.x;   // b*1024 + n
    out[g] = bias[g & (NK - 1)];
}

// Tile (tr,tc) = quadrant (qr,qc) of window (tr-qr, tc-qc): bijective.
// Block = one tile x 16 batches, 20KB LDS -> 8 blocks/CU (32 waves = full).
// Stage: x via async global_load_lds (linear LDS dest, XOR-involution source
//   swizzle, rule #21); this wave's 1KB quadrant weights -> LDS (4KB/block).
// Compute: LDS-ONLY inner loop (no global latency): lane (p,bl) handles
//   chunks kq = 4j+p of batch bl -> both x and w ds_read_b128 at the minimal
//   8-access/bank pattern (w reads are 16-lane broadcasts of 4 addresses on
//   4 distinct bank-groups). shfl_xor(16,32) combines parts; p==0 lanes
//   atomicAdd out[b][n].
__global__ __launch_bounds__(256, 8)
void bslc_main(const float* __restrict__ x,
               const float* __restrict__ w,
               float* __restrict__ out)
{
    __shared__ float4 xs[16 * 64];   // 16 KiB: [bl][slot], slot = chunk ^ bl
    __shared__ float4 wl[4 * 64];    // 4 KiB:  [q][kq]

    // Bijective XCD-chunked swizzle (m204): 4356 = 8*544 + 4.
    const int hw = blockIdx.x;
    const int xcd = hw & 7, sl = hw >> 3;
    const int q8 = NBLK >> 3, r8 = NBLK & 7;          // 544, 4
    const int work = (xcd < r8 ? xcd * (q8 + 1)
                               : r8 * (q8 + 1) + (xcd - r8) * q8) + sl;

    const int bg  = work & 3;        // 4 bgs of a tile adjacent -> L1/L2 w reuse
    const int lin = work >> 2;
    const int tr = lin / NTT, tc = lin % NTT;

    const int t = threadIdx.x, lane = t & 63, wv = t >> 6;

    // This wave's window (quadrant wv of window (tr-qr, tc-qc)).
    const int qr = wv >> 1, qc = wv & 1;
    const int nr = tr - qr, nc = tc - qc;
    const bool valid = (nr >= 0) & (nr < NKH) & (nc >= 0) & (nc < NKW);
    const int n = nr * NKW + nc;

    // ---- weight stage: 1KB per wave, one float4 per lane ----
    if (valid) {
        const int kq = lane;                         // row kq>>2, colchunk kq&3
        const size_t off = (size_t)n * 1024
                         + (size_t)(qr * 16 + (kq >> 2)) * 32
                         + qc * 16 + (kq & 3) * 4;
        wl[wv * 64 + kq] = *reinterpret_cast<const float4*>(w + off);
    }

    // ---- x stage ----
    const int r0 = tr * 16 - 8, c0 = tc * 16 - 8;
    const bool interior = (tr >= 1) & (tr <= 31) & (tc >= 1) & (tc <= 31);

    if (interior) {
#pragma unroll
        for (int ii = 0; ii < 4; ++ii) {
            const int bl = 4 * ii + wv;              // wave-uniform
            const int c  = lane ^ bl;                // chunk this lane fetches
            const float* gp = x + (size_t)(bg * 16 + bl) * IMG_SZ
                            + (size_t)(r0 + (c >> 2)) * IMG_W
                            + c0 + (c & 3) * 4;
            __builtin_amdgcn_global_load_lds(
                (g_char_t*)gp, (lds_char_t*)&xs[bl * 64], 16, 0, 0);
        }
    } else {
#pragma unroll
        for (int ii = 0; ii < 4; ++ii) {
            const int bl = 4 * ii + wv;
            const int c  = lane ^ bl;
            const int rimg = r0 + (c >> 2);
            const int cimg = c0 + (c & 3) * 4;
            float4 v = make_float4(0.f, 0.f, 0.f, 0.f);
            if (rimg >= 0 && rimg < IMG_H && cimg >= 0 && cimg < IMG_W)
                v = *reinterpret_cast<const float4*>(
                    x + (size_t)(bg * 16 + bl) * IMG_SZ
                      + (size_t)rimg * IMG_W + cimg);
            xs[bl * 64 + lane] = v;                  // slot=lane, chunk=lane^bl
        }
    }
    __syncthreads();

    if (!valid) return;                              // wave-uniform

    // ---- compute: LDS-only ----
    const int p  = lane >> 4;        // part 0..3
    const int bl = lane & 15;        // batch within block

    float a0 = 0.f, a1 = 0.f, a2 = 0.f, a3 = 0.f;
#pragma unroll
    for (int j = 0; j < 16; ++j) {
        const int kq = 4 * j + p;                    // bank-spread across p
        const float4 xv  = xs[bl * 64 + (kq ^ bl)];
        const float4 wv4 = wl[wv * 64 + kq];         // 4-addr broadcast read
        a0 = fmaf(xv.x, wv4.x, a0);
        a1 = fmaf(xv.y, wv4.y, a1);
        a2 = fmaf(xv.z, wv4.z, a2);
        a3 = fmaf(xv.w, wv4.w, a3);
    }
    float s = (a0 + a1) + (a2 + a3);
    s += __shfl_xor(s, 16, 64);                      // combine parts
    s += __shfl_xor(s, 32, 64);
    if (p == 0)                                      // lanes 0..15: batch bl
        atomicAdd(&out[(size_t)(bg * 16 + bl) * NK + n], s);
}

extern "C" void kernel_launch(void* const* d_in, const int* in_sizes, int n_in,
                              void* d_out, int out_size, void* d_ws, size_t ws_size,
                              hipStream_t stream) {
    const float* x    = (const float*)d_in[0];  // (64,1,512,512) fp32
    const float* wgt  = (const float*)d_in[1];  // (1024,1024) fp32
    const float* bias = (const float*)d_in[2];  // (1024,) fp32
    float* out        = (float*)d_out;          // (64,32,32) fp32

    bslc_init<<<dim3(BATCH * NK / 256), 256, 0, stream>>>(bias, out);
    bslc_main<<<dim3(NBLK), 256, 0, stream>>>(x, wgt, out);
}